// Round 6
// baseline (276.135 us; speedup 1.0000x reference)
//
#include <hip/hip_runtime.h>

#define NN 100000
#define NE 6400000
#define NEG_SLOPE 0.2f

// ---- binned path geometry ----
#define SLICE 400              // nodes per bin (sacc = 400*3 floats = 4.8 KB)
#define NSLICE 250             // 250 * 400 = 100000 = NN exactly
#define ABLK 256               // hist/scatter blocks
#define EPB (NE / ABLK)        // 25000 edges per block, %4 == 0

// ---- fallback (r5) geometry ----
#define FSLICE 10240
#define FNSLICE 10
#define FNCHUNK 20
#define FCHUNK (NE / FNCHUNK)

// ---------------- node pass: pack={h0,h1,a_src,a_dst}, scalar tables -------
__global__ void gat_node(const float* __restrict__ x, const float* __restrict__ W,
                         const float* __restrict__ att_src, const float* __restrict__ att_dst,
                         float4* __restrict__ pack, float* __restrict__ asrc,
                         float* __restrict__ adst, int n) {
    int gtid = blockIdx.x * blockDim.x + threadIdx.x;
    int wave = gtid >> 6, lane = threadIdx.x & 63;
    int nw = (gridDim.x * blockDim.x) >> 6;
    float as0 = att_src[0], as1 = att_src[1];
    float ad0 = att_dst[0], ad1 = att_dst[1];
    for (int node = wave; node < n; node += nw) {
        float2 xx = *(const float2*)(x + (size_t)node * 128 + lane * 2);
        float2 w0 = *(const float2*)(W + lane * 4);
        float2 w1 = *(const float2*)(W + lane * 4 + 2);
        float c0 = xx.x * w0.x + xx.y * w1.x;
        float c1 = xx.x * w0.y + xx.y * w1.y;
        #pragma unroll
        for (int off = 32; off; off >>= 1) {
            c0 += __shfl_down(c0, off);
            c1 += __shfl_down(c1, off);
        }
        if (lane == 0) {
            float s = c0 * as0 + c1 * as1;
            float d = c0 * ad0 + c1 * ad1;
            pack[node] = make_float4(c0, c1, s, d);
            asrc[node] = s;
            adst[node] = d;
        }
    }
}

// ---------------- phase A1: per-(block,bin) histogram ----------------------
__global__ __launch_bounds__(1024) void
gat_hist(const int* __restrict__ dst, int* __restrict__ cnt) {
    __shared__ unsigned h[NSLICE];
    const int ablk = blockIdx.x, t = threadIdx.x;
    if (t < NSLICE) h[t] = 0;
    __syncthreads();
    const int b0 = ablk * EPB;
    for (int o = t * 4; o < EPB; o += 4096) {
        int4 d4 = *(const int4*)(dst + b0 + o);
        const int* dp = (const int*)&d4;
        #pragma unroll
        for (int u = 0; u < 4; ++u)
            atomicAdd(&h[(unsigned)dp[u] / SLICE], 1u);
    }
    __syncthreads();
    if (t < NSLICE) cnt[t * ABLK + ablk] = (int)h[t];
}

// ---------------- phase A2: exact prefix -> per-(bin,block) bases ----------
__global__ __launch_bounds__(256) void
gat_prefix(int* __restrict__ cnt, int* __restrict__ binstart) {
    __shared__ int tot[NSLICE];
    __shared__ int bst[NSLICE + 1];
    const int t = threadIdx.x;
    if (t < NSLICE) {
        int sum = 0;
        #pragma unroll 8
        for (int a = 0; a < ABLK; ++a) sum += cnt[t * ABLK + a];
        tot[t] = sum;
    }
    __syncthreads();
    if (t == 0) {
        int run = 0;
        for (int b = 0; b < NSLICE; ++b) { bst[b] = run; run += tot[b]; }
        bst[NSLICE] = run;
    }
    __syncthreads();
    if (t < NSLICE) {
        int run = bst[t];
        #pragma unroll 8
        for (int a = 0; a < ABLK; ++a) {
            int c = cnt[t * ABLK + a];
            cnt[t * ABLK + a] = run;
            run += c;
        }
    }
    if (t <= NSLICE) binstart[t] = bst[t];
}

// ---------------- phase A3: scatter records into block-private ranges ------
// record = {packed: off(9b)<<17 | src(17b), ea bits}; no global atomics.
__global__ __launch_bounds__(1024) void
gat_scatter(const int* __restrict__ src, const int* __restrict__ dst,
            const float* __restrict__ ea, const int* __restrict__ base,
            uint2* __restrict__ recs) {
    __shared__ unsigned cursor[NSLICE];
    const int ablk = blockIdx.x, t = threadIdx.x;
    if (t < NSLICE) cursor[t] = (unsigned)base[t * ABLK + ablk];
    __syncthreads();
    const int b0 = ablk * EPB;
    for (int o = t * 4; o < EPB; o += 4096) {
        const int i = b0 + o;
        int4 s4 = *(const int4*)(src + i);
        int4 d4 = *(const int4*)(dst + i);
        float4 e4 = *(const float4*)(ea + i);
        const int* sp = (const int*)&s4;
        const int* dp = (const int*)&d4;
        const float* ep = (const float*)&e4;
        #pragma unroll
        for (int u = 0; u < 4; ++u) {
            unsigned d = (unsigned)dp[u];
            unsigned bin = d / SLICE;
            unsigned off = d - bin * SLICE;
            unsigned pos = atomicAdd(&cursor[bin], 1u);
            recs[pos] = make_uint2((off << 17) | (unsigned)sp[u], __float_as_uint(ep[u]));
        }
    }
}

// ---------------- phase B: one block per slice, direct final output --------
__global__ __launch_bounds__(1024) void
gat_scan(const uint2* __restrict__ recs, const int* __restrict__ binstart,
         const float4* __restrict__ pack, const float* __restrict__ adst,
         const float* __restrict__ W_edge, const float* __restrict__ att_edge,
         const float* __restrict__ bias,
         float* __restrict__ out, float* __restrict__ invd) {
    __shared__ float sacc[SLICE * 3];
    __shared__ float sadst[SLICE];
    const int s = blockIdx.x, t = threadIdx.x;
    for (int j = t; j < SLICE * 3; j += 1024) sacc[j] = 0.f;
    if (t < SLICE) sadst[t] = adst[s * SLICE + t];
    __syncthreads();
    const float k = W_edge[0] * att_edge[0] + W_edge[1] * att_edge[1];
    const int start = binstart[s], end = binstart[s + 1];
    int i = start + t;
    for (; i + 3072 < end; i += 4096) {               // 4-batched: loads first
        uint2 r0 = recs[i], r1 = recs[i + 1024], r2 = recs[i + 2048], r3 = recs[i + 3072];
        float4 p0 = pack[r0.x & 0x1FFFF];
        float4 p1 = pack[r1.x & 0x1FFFF];
        float4 p2 = pack[r2.x & 0x1FFFF];
        float4 p3 = pack[r3.x & 0x1FFFF];
        uint2 rr[4] = {r0, r1, r2, r3};
        float4 pp[4] = {p0, p1, p2, p3};
        #pragma unroll
        for (int u = 0; u < 4; ++u) {
            unsigned off = rr[u].x >> 17;
            float al = pp[u].z + sadst[off] + k * __uint_as_float(rr[u].y);
            al = al > 0.f ? al : NEG_SLOPE * al;
            float ex = __expf(al);
            atomicAdd(&sacc[off * 3],     ex);
            atomicAdd(&sacc[off * 3 + 1], ex * pp[u].x);
            atomicAdd(&sacc[off * 3 + 2], ex * pp[u].y);
        }
    }
    for (; i < end; i += 1024) {                      // tail
        uint2 r = recs[i];
        float4 p = pack[r.x & 0x1FFFF];
        unsigned off = r.x >> 17;
        float al = p.z + sadst[off] + k * __uint_as_float(r.y);
        al = al > 0.f ? al : NEG_SLOPE * al;
        float ex = __expf(al);
        atomicAdd(&sacc[off * 3],     ex);
        atomicAdd(&sacc[off * 3 + 1], ex * p.x);
        atomicAdd(&sacc[off * 3 + 2], ex * p.y);
    }
    __syncthreads();
    if (t < SLICE) {
        float de = sacc[t * 3], n0 = sacc[t * 3 + 1], n1 = sacc[t * 3 + 2];
        float inv = 1.0f / (de + 1e-16f);
        int node = s * SLICE + t;
        *(float2*)(out + 2 * node) = make_float2(n0 * inv + bias[0], n1 * inv + bias[1]);
        invd[node] = inv;
    }
}

// ---------------- alpha pass: recompute ex, alpha = ex * invd[dst] ---------
__global__ void gat_alpha(const int* __restrict__ src, const int* __restrict__ dst,
                          const float* __restrict__ ea,
                          const float* __restrict__ asrc, const float* __restrict__ adst,
                          const float* __restrict__ W_edge, const float* __restrict__ att_edge,
                          const float* __restrict__ invd, float* __restrict__ alpha) {
    const float k = W_edge[0] * att_edge[0] + W_edge[1] * att_edge[1];
    int i = (blockIdx.x * blockDim.x + threadIdx.x) * 4;
    if (i >= NE) return;
    int4   d4 = *(const int4*)(dst + i);
    int4   s4 = *(const int4*)(src + i);
    float4 e4 = *(const float4*)(ea + i);
    const int*   dp = (const int*)&d4;
    const int*   sp = (const int*)&s4;
    const float* ep = (const float*)&e4;
    float as[4], ad[4], iv[4];
    #pragma unroll
    for (int u = 0; u < 4; ++u) {
        as[u] = asrc[sp[u]];
        ad[u] = adst[dp[u]];
        iv[u] = invd[dp[u]];
    }
    float4 a;
    float* ap = (float*)&a;
    #pragma unroll
    for (int u = 0; u < 4; ++u) {
        float al = as[u] + ad[u] + k * ep[u];
        al = al > 0.0f ? al : NEG_SLOPE * al;
        ap[u] = __expf(al) * iv[u];
    }
    *(float4*)(alpha + i) = a;
}

// ================== fallback (r5) kernels — used only if ws is small =======
__global__ __launch_bounds__(1024) void
gat_scan_fb(const int* __restrict__ src, const int* __restrict__ dst,
            const float* __restrict__ ea, const float4* __restrict__ pack,
            const float* __restrict__ adst,
            const float* __restrict__ W_edge, const float* __restrict__ att_edge,
            float* __restrict__ partial) {
    __shared__ float sacc[FSLICE * 3];
    const int s = blockIdx.x / FNCHUNK;
    const int c = blockIdx.x % FNCHUNK;
    const int lo = s * FSLICE;
    for (int j = threadIdx.x; j < FSLICE * 3; j += 1024) sacc[j] = 0.0f;
    __syncthreads();
    const float k = W_edge[0] * att_edge[0] + W_edge[1] * att_edge[1];
    const int base = c * FCHUNK;
    for (int o = threadIdx.x * 8; o < FCHUNK; o += 1024 * 8) {
        const int i = base + o;
        int4   da = *(const int4*)(dst + i), db = *(const int4*)(dst + i + 4);
        int4   sa = *(const int4*)(src + i), sb = *(const int4*)(src + i + 4);
        float4 e0 = *(const float4*)(ea + i), e1 = *(const float4*)(ea + i + 4);
        int   dd[8] = {da.x, da.y, da.z, da.w, db.x, db.y, db.z, db.w};
        int   ss[8] = {sa.x, sa.y, sa.z, sa.w, sb.x, sb.y, sb.z, sb.w};
        float ee[8] = {e0.x, e0.y, e0.z, e0.w, e1.x, e1.y, e1.z, e1.w};
        unsigned off[8];
        float4 ps[8];
        float  ad[8];
        #pragma unroll
        for (int u = 0; u < 8; ++u) {
            off[u] = (unsigned)(dd[u] - lo);
            bool acc = off[u] < FSLICE;
            ps[u] = pack[acc ? ss[u] : 0];
            ad[u] = adst[acc ? dd[u] : lo];
        }
        #pragma unroll
        for (int u = 0; u < 8; ++u) {
            float al = ps[u].z + ad[u] + k * ee[u];
            al = al > 0.0f ? al : NEG_SLOPE * al;
            float ex = __expf(al);
            if (off[u] < FSLICE) {
                atomicAdd(&sacc[off[u] * 3],     ex);
                atomicAdd(&sacc[off[u] * 3 + 1], ex * ps[u].x);
                atomicAdd(&sacc[off[u] * 3 + 2], ex * ps[u].y);
            }
        }
    }
    __syncthreads();
    float* pout = partial + (size_t)blockIdx.x * (FSLICE * 3);
    for (int j = threadIdx.x; j < FSLICE * 3; j += 1024) pout[j] = sacc[j];
}

__global__ void gat_combine_fb(const float* __restrict__ partial,
                               const float* __restrict__ bias,
                               float* __restrict__ out, float* __restrict__ invd) {
    int n = blockIdx.x * blockDim.x + threadIdx.x;
    if (n >= NN) return;
    int sl = n / FSLICE, off = n % FSLICE;
    const float* p = partial + (size_t)sl * FNCHUNK * (FSLICE * 3) + (size_t)off * 3;
    float de = 0.f, n0 = 0.f, n1 = 0.f;
    for (int c = 0; c < FNCHUNK; ++c, p += FSLICE * 3) {
        de += p[0]; n0 += p[1]; n1 += p[2];
    }
    float inv = 1.0f / (de + 1e-16f);
    out[2 * n]     = n0 * inv + bias[0];
    out[2 * n + 1] = n1 * inv + bias[1];
    invd[n] = inv;
}

extern "C" void kernel_launch(void* const* d_in, const int* in_sizes, int n_in,
                              void* d_out, int out_size, void* d_ws, size_t ws_size,
                              hipStream_t stream) {
    const float* x        = (const float*)d_in[0];
    const int*   ei       = (const int*)  d_in[1];
    const float* ea       = (const float*)d_in[2];
    const float* W_src    = (const float*)d_in[3];
    const float* W_edge   = (const float*)d_in[4];
    const float* att_src  = (const float*)d_in[5];
    const float* att_dst  = (const float*)d_in[6];
    const float* att_edge = (const float*)d_in[7];
    const float* bias     = (const float*)d_in[8];

    float* out   = (float*)d_out;      // [N,2]
    float* alpha = out + 2 * NN;       // [E]

    const int* src = ei;
    const int* dst = ei + NE;

    // primary layout: recs | pack | asrc | adst | invd | cnt | binstart
    size_t need = (size_t)NE * 8 + (size_t)NN * 16 + 3 * (size_t)NN * 4
                + (size_t)NSLICE * ABLK * 4 + (NSLICE + 1) * 4 + 64;

    if (ws_size >= need) {
        uint2*  recs = (uint2*)d_ws;
        float4* pack = (float4*)((char*)d_ws + (size_t)NE * 8);
        float*  asrc = (float*)(pack + NN);
        float*  adst = asrc + NN;
        float*  invd = adst + NN;
        int*    cnt  = (int*)(invd + NN);
        int*    binstart = cnt + NSLICE * ABLK;

        gat_node   <<<1024, 256, 0, stream>>>(x, W_src, att_src, att_dst, pack, asrc, adst, NN);
        gat_hist   <<<ABLK, 1024, 0, stream>>>(dst, cnt);
        gat_prefix <<<1, 256, 0, stream>>>(cnt, binstart);
        gat_scatter<<<ABLK, 1024, 0, stream>>>(src, dst, ea, cnt, recs);
        gat_scan   <<<NSLICE, 1024, 0, stream>>>(recs, binstart, pack, adst,
                                                 W_edge, att_edge, bias, out, invd);
        gat_alpha  <<<NE / (256 * 4), 256, 0, stream>>>(src, dst, ea, asrc, adst,
                                                        W_edge, att_edge, invd, alpha);
    } else {
        // fallback: r5 slice-rescan, partial slabs in the alpha region
        float4* pack = (float4*)d_ws;
        float*  asrc = (float*)(pack + NN);
        float*  adst = asrc + NN;
        float*  invd = adst + NN;
        float*  partial = alpha;       // 200 * 30720 = 6.144M floats <= 6.4M

        gat_node      <<<1024, 256, 0, stream>>>(x, W_src, att_src, att_dst, pack, asrc, adst, NN);
        gat_scan_fb   <<<FNSLICE * FNCHUNK, 1024, 0, stream>>>(src, dst, ea, pack, adst,
                                                               W_edge, att_edge, partial);
        gat_combine_fb<<<(NN + 255) / 256, 256, 0, stream>>>(partial, bias, out, invd);
        gat_alpha     <<<NE / (256 * 4), 256, 0, stream>>>(src, dst, ea, asrc, adst,
                                                           W_edge, att_edge, invd, alpha);
    }
}